// Round 9
// baseline (321.297 us; speedup 1.0000x reference)
//
#include <hip/hip_runtime.h>

#define B_  32
#define C_  384
#define HW_ 784
#define N_  25088   // B_*HW_
#define K_  2048
#define PPX 112     // pixels per fin block; 7*112=784

#define OFF_F    0
#define OFF_Q    9633792
#define OFF_ASG  19267584
#define OFF_DIST 70647808

#define MARGIN 0.02f

typedef unsigned short u16;
typedef unsigned int u32;
typedef __attribute__((ext_vector_type(8))) short short8;
typedef __attribute__((ext_vector_type(4))) float floatx4;
typedef __attribute__((ext_vector_type(4))) float f32x4;
typedef __attribute__((ext_vector_type(4))) u16 u16x4;
typedef __attribute__((ext_vector_type(8))) u16 u16x8;

static __device__ __forceinline__ u16 f2bf(float x) {
    u32 u = __builtin_bit_cast(u32, x);
    u32 r = (u + 0x7FFFu + ((u >> 16) & 1u)) >> 16;
    return (u16)r;
}
static __device__ __forceinline__ float bf2f(u16 v) {
    return __builtin_bit_cast(float, (u32)v << 16);
}

static __device__ __forceinline__ void gload_lds16(const void* g, void* l) {
    __builtin_amdgcn_global_load_lds(
        (const __attribute__((address_space(1))) unsigned int*)g,
        (__attribute__((address_space(3))) unsigned int*)l,
        16, 0, 0);
}

// fallback-path scratch slots in the q output region
static __device__ __forceinline__ size_t qslot(int b, int s, int hw) {
    return ((size_t)b * C_ + s) * HW_ + hw;
}

// ---------------- K1: feat -> f, inv_n, a_hi  AND  codebook -> code_n, b_hi ----------------
__global__ __launch_bounds__(256) void k_prep(const float* __restrict__ feat,
                                              const float* __restrict__ cb,
                                              float* __restrict__ f_out,
                                              float* __restrict__ inv_n,
                                              u16* __restrict__ a_hi,
                                              float* __restrict__ code_n,
                                              u16* __restrict__ b_hi) {
    int tid = threadIdx.x;
    if (blockIdx.x >= 1568) {
        int row  = (blockIdx.x - 1568) * 4 + (tid >> 6);
        int lane = tid & 63;
        const float* src = cb + (size_t)row * C_;
        float v[6];
        float ss = 0.f;
#pragma unroll
        for (int i = 0; i < 6; ++i) { v[i] = src[lane + 64 * i]; ss += v[i] * v[i]; }
#pragma unroll
        for (int off = 32; off; off >>= 1) ss += __shfl_xor(ss, off, 64);
        float inv = 1.f / fmaxf(sqrtf(ss), 1e-12f);
#pragma unroll
        for (int i = 0; i < 6; ++i) {
            float vn = v[i] * inv;
            code_n[(size_t)row * C_ + lane + 64 * i] = vn;
            b_hi  [(size_t)row * C_ + lane + 64 * i] = f2bf(vn);
        }
        return;
    }
    __shared__ float tile[C_][17];
    __shared__ float red[16][17];
    __shared__ float s_inv[16];
    int b   = blockIdx.x / 49;
    int hw0 = (blockIdx.x - b * 49) * 16;
    int px  = tid & 15, cq = tid >> 4;

#pragma unroll
    for (int it = 0; it < 24; ++it) {
        int c = cq + 16 * it;
        tile[c][px] = feat[((size_t)(b * C_ + c)) * HW_ + hw0 + px];
    }
    __syncthreads();
    float ss = 0.f;
#pragma unroll
    for (int q = 0; q < 24; ++q) {
        float v = tile[cq + 16 * q][px];
        ss = fmaf(v, v, ss);
    }
    red[cq][px] = ss;
    __syncthreads();
    if (tid < 16) {
        float tot = 0.f;
#pragma unroll
        for (int p = 0; p < 16; ++p) tot += red[p][tid];
        float inv = 1.f / fmaxf(sqrtf(tot), 1e-12f);
        s_inv[tid] = inv;
        inv_n[(size_t)b * HW_ + hw0 + tid] = inv;
    }
    __syncthreads();

    {
        int p2 = tid >> 4, cc = tid & 15;
        float* fb = f_out + ((size_t)(b * HW_ + hw0 + p2)) * C_;
#pragma unroll
        for (int it = 0; it < 6; ++it) {
            int c0 = cc * 4 + 64 * it;
            f32x4 v;
            v[0] = tile[c0 + 0][p2];
            v[1] = tile[c0 + 1][p2];
            v[2] = tile[c0 + 2][p2];
            v[3] = tile[c0 + 3][p2];
            __builtin_nontemporal_store(v, (f32x4*)(fb + c0));
        }
    }
    {
        int p2 = tid >> 4, cc = tid & 15;
        float inv = s_inv[p2];
        u16* aptr = a_hi + ((size_t)(b * HW_ + hw0 + p2)) * C_;
#pragma unroll
        for (int it = 0; it < 12; ++it) {
            int c0 = 2 * cc + 32 * it;
            u16 h0 = f2bf(tile[c0][p2] * inv);
            u16 h1 = f2bf(tile[c0 + 1][p2] * inv);
            *(u32*)(aptr + c0) = (u32)h0 | ((u32)h1 << 16);
        }
    }
}

// ---------------- K2: bf16 MFMA GEMM; DB: also write bf16 dist shadow, NT fp32 dist ----------------
template <bool DB>
__global__ __launch_bounds__(256) void k_gemm(const u16* __restrict__ A,
                                              const u16* __restrict__ Bm,
                                              float* __restrict__ D,
                                              u16* __restrict__ db) {
    __shared__ u16 As[2][128 * 32];
    __shared__ u16 Bs[2][128 * 32];
    int tid = threadIdx.x;
    int lin = blockIdx.x;
    int swz = (lin & 7) * 392 + (lin >> 3);   // 3136 = 8 * 392, bijective
    int n0 = (swz & 15) * 128;
    int m0 = (swz >> 4) * 128;
    int w = tid >> 6, l = tid & 63;
    int wm = (w >> 1) * 64, wn = (w & 1) * 64;
    int q4 = l >> 4, r15 = l & 15;

    floatx4 acc[4][4];
#pragma unroll
    for (int i = 0; i < 4; ++i)
#pragma unroll
        for (int j = 0; j < 4; ++j) acc[i][j] = (floatx4)0.f;

    int srow = tid >> 2;
    int sp   = tid & 3;
    int fs   = (srow ^ (srow >> 2)) & 3;
    int kk0  = 8 * (sp ^ fs);

#define STAGE(buf, kt)                                                          \
    {                                                                           \
        _Pragma("unroll")                                                       \
        for (int q = 0; q < 2; ++q) {                                           \
            int row = q * 64 + srow;                                            \
            int off = (q * 256 + tid) * 16;                                     \
            gload_lds16(A  + (size_t)(m0 + row) * C_ + (kt) + kk0,              \
                        (char*)As[buf] + off);                                  \
            gload_lds16(Bm + (size_t)(n0 + row) * C_ + (kt) + kk0,              \
                        (char*)Bs[buf] + off);                                  \
        }                                                                       \
    }

    STAGE(0, 0);
    __syncthreads();

    const int slot = (q4 ^ ((r15 ^ (r15 >> 2)) & 3)) << 4;
#pragma unroll 1
    for (int t = 0; t < 12; ++t) {
        int cur = t & 1;
        if (t < 11) STAGE(cur ^ 1, (t + 1) * 32);
        const char* Ab = (const char*)As[cur];
        const char* Bb = (const char*)Bs[cur];
        short8 a[4], b[4];
#pragma unroll
        for (int i = 0; i < 4; ++i) {
            a[i] = *(const short8*)(Ab + (wm + i * 16 + r15) * 64 + slot);
            b[i] = *(const short8*)(Bb + (wn + i * 16 + r15) * 64 + slot);
        }
#pragma unroll
        for (int i = 0; i < 4; ++i)
#pragma unroll
            for (int j = 0; j < 4; ++j)
                acc[i][j] = __builtin_amdgcn_mfma_f32_16x16x32_bf16(a[i], b[j], acc[i][j], 0, 0, 0);
        __syncthreads();
    }

#pragma unroll
    for (int i = 0; i < 4; ++i) {
        int gm = m0 + wm + i * 16 + q4 * 4;
#pragma unroll
        for (int j = 0; j < 4; ++j) {
            int gn = n0 + wn + j * 16 + r15;
#pragma unroll
            for (int r = 0; r < 4; ++r) {
                float d = 2.f - 2.f * acc[i][j][r];
                if (DB) {
                    __builtin_nontemporal_store(d, D + (size_t)(gm + r) * K_ + gn);
                    db[(size_t)(gm + r) * K_ + gn] = f2bf(d);
                } else {
                    D[(size_t)(gm + r) * K_ + gn] = d;
                }
            }
        }
    }
#undef STAGE
}

// ---------------- K3 (big path): fused stats + assignment + recheck + q ----------------
__global__ __launch_bounds__(256) void k_fin(const u16* __restrict__ db,
                                             const float* __restrict__ codeN,
                                             const float* __restrict__ invN,
                                             const float* __restrict__ f_in,
                                             float* __restrict__ asg,
                                             float* __restrict__ qOut) {
    __shared__ float tbuf[64][113];
    __shared__ float s_inv[PPX], s_thr[PPX];
    __shared__ int   s_cnt[PPX], s_amin[PPX];
    __shared__ int   s_cand[PPX][16];
    int tile = blockIdx.x;
    int b    = tile / 7;
    int hw0  = (tile - b * 7) * PPX;
    int n0   = b * HW_ + hw0;
    int tid  = threadIdx.x;
    int w = tid >> 6, l = tid & 63;

    if (tid < PPX) s_cnt[tid] = 0;

    // ---- pass 1: per-row stats (esum, dmin) from bf16 shadow ----
#pragma unroll 1
    for (int r = w; r < PPX; r += 4) {
        const u16* dr = db + (size_t)(n0 + r) * K_;
        float es = 0.f, dm = 3.4e38f;
#pragma unroll
        for (int i = 0; i < 4; ++i) {
            u16x8 v = *(const u16x8*)(dr + l * 8 + 512 * i);
#pragma unroll
            for (int e = 0; e < 8; ++e) {
                float d = bf2f(v[e]);
                es += __expf(-10.f * d);
                dm = fminf(dm, d);
            }
        }
#pragma unroll
        for (int off = 32; off; off >>= 1) {
            es += __shfl_xor(es, off, 64);
            dm = fminf(dm, __shfl_xor(dm, off, 64));
        }
        if (l == 0) {
            s_inv[r] = 1.f / es;
            s_thr[r] = dm + MARGIN;
        }
    }
    __syncthreads();

    // ---- pass 2: assignment (L3-hot re-read) + candidate collection ----
    int r16 = tid >> 4, c4 = (tid & 15) * 4;
    int px = tid & 127, kg = tid >> 7;
#pragma unroll 1
    for (int ch = 0; ch < 32; ++ch) {
        int k0 = ch * 64;
#pragma unroll
        for (int rr = 0; rr < 7; ++rr) {
            int row = r16 + 16 * rr;
            u16x4 dv = *(const u16x4*)(db + (size_t)(n0 + row) * K_ + k0 + c4);
            float inv = s_inv[row], thr = s_thr[row];
#pragma unroll
            for (int cc = 0; cc < 4; ++cc) {
                float d = bf2f(dv[cc]);
                tbuf[c4 + cc][row] = __expf(-10.f * d) * inv;
                if (d <= thr) {
                    int idx = atomicAdd(&s_cnt[row], 1);
                    if (idx < 16) s_cand[row][idx] = k0 + c4 + cc;
                }
            }
        }
        __syncthreads();
        if (px < PPX) {
            size_t base = ((size_t)(b * K_ + k0 + kg * 32)) * HW_ + hw0 + px;
#pragma unroll
            for (int ki = 0; ki < 32; ++ki)
                __builtin_nontemporal_store(tbuf[kg * 32 + ki][px],
                                            asg + base + (size_t)ki * HW_);
        }
        __syncthreads();
    }

    if (tid < PPX) s_amin[tid] = s_cand[tid][0];
    __syncthreads();

    // ---- pass 3: exact fp32 recheck for ambiguous rows ----
#pragma unroll 1
    for (int r = w; r < PPX; r += 4) {
        int cnt = s_cnt[r];
        if (cnt < 2) continue;
        cnt = cnt > 16 ? 16 : cnt;
        float ivn = invN[n0 + r];
        float fv[6];
        const float* frow = f_in + (size_t)(n0 + r) * C_;
#pragma unroll
        for (int ii = 0; ii < 6; ++ii)
            fv[ii] = frow[l + 64 * ii] * ivn;
        float dbest = 3.4e38f;
        int   kbest = -1;
        for (int ci = 0; ci < cnt; ++ci) {
            int k = s_cand[r][ci];
            float dt = 0.f;
            const float* cr = codeN + (size_t)k * C_;
#pragma unroll
            for (int ii = 0; ii < 6; ++ii) dt = fmaf(fv[ii], cr[l + 64 * ii], dt);
#pragma unroll
            for (int off = 1; off < 64; off <<= 1) dt += __shfl_xor(dt, off, 64);
            float dex = 2.f - 2.f * dt;
            if (kbest < 0 || dex < dbest || (dex == dbest && k < kbest)) { dbest = dex; kbest = k; }
        }
        if (l == 0) s_amin[r] = kbest;
    }
    __syncthreads();

    // ---- q gather (CHW), 448B coalesced NT segments ----
    if (px < PPX) {
        const float* cr = codeN + (size_t)s_amin[px] * C_ + kg * 192;
        size_t qb = ((size_t)b * C_ + kg * 192) * HW_ + hw0 + px;
#pragma unroll 1
        for (int c4i = 0; c4i < 48; ++c4i) {
            float4 v = *(const float4*)(cr + 4 * c4i);
            __builtin_nontemporal_store(v.x, qOut + qb + (size_t)(4 * c4i + 0) * HW_);
            __builtin_nontemporal_store(v.y, qOut + qb + (size_t)(4 * c4i + 1) * HW_);
            __builtin_nontemporal_store(v.z, qOut + qb + (size_t)(4 * c4i + 2) * HW_);
            __builtin_nontemporal_store(v.w, qOut + qb + (size_t)(4 * c4i + 3) * HW_);
        }
    }
}

// ---------------- fallback path kernels (small ws): round-8 proven chain ----------------
__global__ __launch_bounds__(256) void k_stats_f(const float* __restrict__ D,
                                                 float2* __restrict__ srow) {
    int row = blockIdx.x * 4 + (threadIdx.x >> 6);
    int l   = threadIdx.x & 63;
    const float* dr = D + (size_t)row * K_;
    float es = 0.f, dm = 3.4e38f;
#pragma unroll
    for (int i = 0; i < 8; ++i) {
        float4 v = *(const float4*)(dr + l * 4 + 256 * i);
        es += __expf(-10.f * v.x) + __expf(-10.f * v.y)
            + __expf(-10.f * v.z) + __expf(-10.f * v.w);
        dm = fminf(dm, fminf(fminf(v.x, v.y), fminf(v.z, v.w)));
    }
#pragma unroll
    for (int off = 32; off; off >>= 1) {
        es += __shfl_xor(es, off, 64);
        dm = fminf(dm, __shfl_xor(dm, off, 64));
    }
    if (l == 0) {
        float2 st;
        st.x = 1.f / es;
        st.y = dm + MARGIN;
        srow[row] = st;
    }
}

__global__ __launch_bounds__(256) void k_post_f(const float* __restrict__ D,
                                                const float2* __restrict__ srow,
                                                u32* __restrict__ Qi,
                                                float* __restrict__ asg) {
    __shared__ float tbuf[64][113];
    __shared__ float s_inv[PPX], s_thr[PPX];
    __shared__ int   s_cnt[PPX];
    __shared__ int   s_cand[PPX][16];
    int tile = blockIdx.x;
    int kc   = blockIdx.y;
    int b    = tile / 7;
    int hw0  = (tile - b * 7) * PPX;
    int n0   = b * HW_ + hw0;
    int tid  = threadIdx.x;

    if (tid < PPX) {
        float2 st = srow[n0 + tid];
        s_inv[tid] = st.x;
        s_thr[tid] = st.y;
        s_cnt[tid] = 0;
    }
    __syncthreads();

    int r16 = tid >> 4, c4 = (tid & 15) * 4;
    int px = tid & 127, kg = tid >> 7;
#pragma unroll 1
    for (int ch = 0; ch < 8; ++ch) {
        int k0 = kc * 512 + ch * 64;
#pragma unroll
        for (int rr = 0; rr < 7; ++rr) {
            int row = r16 + 16 * rr;
            f32x4 dv = __builtin_nontemporal_load(
                (const f32x4*)(D + (size_t)(n0 + row) * K_ + k0 + c4));
            float inv = s_inv[row], thr = s_thr[row];
#pragma unroll
            for (int cc = 0; cc < 4; ++cc) {
                float d = dv[cc];
                tbuf[c4 + cc][row] = __expf(-10.f * d) * inv;
                if (d <= thr) {
                    int idx = atomicAdd(&s_cnt[row], 1);
                    if (idx < 16) s_cand[row][idx] = k0 + c4 + cc;
                }
            }
        }
        __syncthreads();
        if (px < PPX) {
            size_t base = ((size_t)(b * K_ + k0 + kg * 32)) * HW_ + hw0 + px;
#pragma unroll
            for (int ki = 0; ki < 32; ++ki)
                __builtin_nontemporal_store(tbuf[kg * 32 + ki][px],
                                            asg + base + (size_t)ki * HW_);
        }
        __syncthreads();
    }

    if (tid < PPX) {
        int cnt = s_cnt[tid];
        cnt = cnt > 16 ? 16 : cnt;
        Qi[qslot(b, kc * 17, hw0 + tid)] = (u32)cnt;
        for (int ci = 0; ci < cnt; ++ci)
            Qi[qslot(b, kc * 17 + 1 + ci, hw0 + tid)] = (u32)s_cand[tid][ci];
    }
}

__global__ __launch_bounds__(256) void k_q(const u32* __restrict__ Qi,
                                           const float* __restrict__ codeN,
                                           const float* __restrict__ invN,
                                           const float* __restrict__ f_in,
                                           float* __restrict__ qOut) {
    __shared__ int s_amin[PPX], s_cnt[PPX];
    __shared__ int s_cand[PPX][64];
    int tile = blockIdx.x;
    int b    = tile / 7;
    int hw0  = (tile - b * 7) * PPX;
    int npix = b * HW_ + hw0;
    int tid  = threadIdx.x;

    if (tid < PPX) {
        int total = 0;
#pragma unroll
        for (int kc = 0; kc < 4; ++kc) {
            int cnt = (int)Qi[qslot(b, kc * 17, hw0 + tid)];
            for (int ci = 0; ci < cnt; ++ci)
                s_cand[tid][total++] = (int)Qi[qslot(b, kc * 17 + 1 + ci, hw0 + tid)];
        }
        s_cnt[tid]  = total;
        s_amin[tid] = s_cand[tid][0];
    }
    __syncthreads();

    int w = tid >> 6, l = tid & 63;
#pragma unroll 1
    for (int r = w; r < PPX; r += 4) {
        int cnt = s_cnt[r];
        if (cnt < 2) continue;
        float ivn = invN[npix + r];
        float fv[6];
        const float* frow = f_in + (size_t)(npix + r) * C_;
#pragma unroll
        for (int ii = 0; ii < 6; ++ii)
            fv[ii] = frow[l + 64 * ii] * ivn;
        float dbest = 3.4e38f;
        int   kbest = -1;
        for (int ci = 0; ci < cnt; ++ci) {
            int k = s_cand[r][ci];
            float dt = 0.f;
            const float* cr = codeN + (size_t)k * C_;
#pragma unroll
            for (int ii = 0; ii < 6; ++ii) dt = fmaf(fv[ii], cr[l + 64 * ii], dt);
#pragma unroll
            for (int off = 1; off < 64; off <<= 1) dt += __shfl_xor(dt, off, 64);
            float dex = 2.f - 2.f * dt;
            if (kbest < 0 || dex < dbest || (dex == dbest && k < kbest)) { dbest = dex; kbest = k; }
        }
        if (l == 0) s_amin[r] = kbest;
    }
    __syncthreads();

    int px = tid & 127, kg = tid >> 7;
    if (px < PPX) {
        const float* cr = codeN + (size_t)s_amin[px] * C_ + kg * 192;
        size_t qb = ((size_t)b * C_ + kg * 192) * HW_ + hw0 + px;
#pragma unroll 1
        for (int c4 = 0; c4 < 48; ++c4) {
            float4 v = *(const float4*)(cr + 4 * c4);
            __builtin_nontemporal_store(v.x, qOut + qb + (size_t)(4 * c4 + 0) * HW_);
            __builtin_nontemporal_store(v.y, qOut + qb + (size_t)(4 * c4 + 1) * HW_);
            __builtin_nontemporal_store(v.z, qOut + qb + (size_t)(4 * c4 + 2) * HW_);
            __builtin_nontemporal_store(v.w, qOut + qb + (size_t)(4 * c4 + 3) * HW_);
        }
    }
}

extern "C" void kernel_launch(void* const* d_in, const int* in_sizes, int n_in,
                              void* d_out, int out_size, void* d_ws, size_t ws_size,
                              hipStream_t stream) {
    const float* feat = (const float*)d_in[0];
    const float* cb   = (const float*)d_in[1];
    float* out    = (float*)d_out;
    float* f_out  = out + OFF_F;
    float* q_out  = out + OFF_Q;
    float* asg    = out + OFF_ASG;   // first 20.8 MB holds a_hi/b_hi until consumed
    float* dist   = out + OFF_DIST;

    u16* a_hi = (u16*)asg;
    u16* b_hi = a_hi + (size_t)N_ * C_;

    const size_t DB_BYTES = (size_t)N_ * K_ * 2;          // 102,760,448
    bool big = ws_size >= DB_BYTES + 3145728 + 100352 + 200704;

    if (big) {
        u16*    db     = (u16*)d_ws;
        float*  code_n = (float*)((char*)d_ws + DB_BYTES);
        float*  inv_n  = (float*)((char*)d_ws + DB_BYTES + 3145728);

        k_prep<<<2080, 256, 0, stream>>>(feat, cb, f_out, inv_n, a_hi, code_n, b_hi);
        k_gemm<true><<<3136, 256, 0, stream>>>(a_hi, b_hi, dist, db);
        k_fin<<<224, 256, 0, stream>>>(db, code_n, inv_n, f_out, asg, q_out);
    } else {
        float*  code_n = (float*)d_ws;
        float*  inv_n  = (float*)((char*)d_ws + 3145728);
        float2* srow   = (float2*)((char*)d_ws + 3246080);
        u32*    Qi     = (u32*)q_out;

        k_prep<<<2080, 256, 0, stream>>>(feat, cb, f_out, inv_n, a_hi, code_n, b_hi);
        k_gemm<false><<<3136, 256, 0, stream>>>(a_hi, b_hi, dist, nullptr);
        k_stats_f<<<N_ / 4, 256, 0, stream>>>(dist, srow);
        k_post_f<<<dim3(224, 4), 256, 0, stream>>>(dist, srow, Qi, asg);
        k_q<<<224, 256, 0, stream>>>(Qi, code_n, inv_n, f_out, q_out);
    }
}

// Round 10
// 277.425 us; speedup vs baseline: 1.1581x; 1.1581x over previous
//
#include <hip/hip_runtime.h>

#define B_  32
#define C_  384
#define HW_ 784
#define N_  25088   // B_*HW_
#define K_  2048
#define PPX 112     // pixels per post/q block; 7*112=784

#define OFF_F    0
#define OFF_Q    9633792
#define OFF_ASG  19267584
#define OFF_DIST 70647808

#define MARGIN 0.02f

typedef unsigned short u16;
typedef unsigned int u32;
typedef __attribute__((ext_vector_type(8))) short short8;
typedef __attribute__((ext_vector_type(4))) float floatx4;
typedef __attribute__((ext_vector_type(4))) float f32x4;
typedef __attribute__((ext_vector_type(4))) u16 u16x4;
typedef __attribute__((ext_vector_type(8))) u16 u16x8;

static __device__ __forceinline__ u16 f2bf(float x) {
    u32 u = __builtin_bit_cast(u32, x);
    u32 r = (u + 0x7FFFu + ((u >> 16) & 1u)) >> 16;
    return (u16)r;
}
static __device__ __forceinline__ float bf2f(u16 v) {
    return __builtin_bit_cast(float, (u32)v << 16);
}

static __device__ __forceinline__ void gload_lds16(const void* g, void* l) {
    __builtin_amdgcn_global_load_lds(
        (const __attribute__((address_space(1))) unsigned int*)g,
        (__attribute__((address_space(3))) unsigned int*)l,
        16, 0, 0);
}

// fallback-path scratch slots in the q output region
static __device__ __forceinline__ size_t qslot(int b, int s, int hw) {
    return ((size_t)b * C_ + s) * HW_ + hw;
}

// ---------------- K1: feat -> f, inv_n, a_hi  AND  codebook -> code_n, b_hi ----------------
__global__ __launch_bounds__(256) void k_prep(const float* __restrict__ feat,
                                              const float* __restrict__ cb,
                                              float* __restrict__ f_out,
                                              float* __restrict__ inv_n,
                                              u16* __restrict__ a_hi,
                                              float* __restrict__ code_n,
                                              u16* __restrict__ b_hi) {
    int tid = threadIdx.x;
    if (blockIdx.x >= 1568) {
        int row  = (blockIdx.x - 1568) * 4 + (tid >> 6);
        int lane = tid & 63;
        const float* src = cb + (size_t)row * C_;
        float v[6];
        float ss = 0.f;
#pragma unroll
        for (int i = 0; i < 6; ++i) { v[i] = src[lane + 64 * i]; ss += v[i] * v[i]; }
#pragma unroll
        for (int off = 32; off; off >>= 1) ss += __shfl_xor(ss, off, 64);
        float inv = 1.f / fmaxf(sqrtf(ss), 1e-12f);
#pragma unroll
        for (int i = 0; i < 6; ++i) {
            float vn = v[i] * inv;
            code_n[(size_t)row * C_ + lane + 64 * i] = vn;
            b_hi  [(size_t)row * C_ + lane + 64 * i] = f2bf(vn);
        }
        return;
    }
    __shared__ float tile[C_][17];
    __shared__ float red[16][17];
    __shared__ float s_inv[16];
    int b   = blockIdx.x / 49;
    int hw0 = (blockIdx.x - b * 49) * 16;
    int px  = tid & 15, cq = tid >> 4;

#pragma unroll
    for (int it = 0; it < 24; ++it) {
        int c = cq + 16 * it;
        tile[c][px] = feat[((size_t)(b * C_ + c)) * HW_ + hw0 + px];
    }
    __syncthreads();
    float ss = 0.f;
#pragma unroll
    for (int q = 0; q < 24; ++q) {
        float v = tile[cq + 16 * q][px];
        ss = fmaf(v, v, ss);
    }
    red[cq][px] = ss;
    __syncthreads();
    if (tid < 16) {
        float tot = 0.f;
#pragma unroll
        for (int p = 0; p < 16; ++p) tot += red[p][tid];
        float inv = 1.f / fmaxf(sqrtf(tot), 1e-12f);
        s_inv[tid] = inv;
        inv_n[(size_t)b * HW_ + hw0 + tid] = inv;
    }
    __syncthreads();

    {
        int p2 = tid >> 4, cc = tid & 15;
        float* fb = f_out + ((size_t)(b * HW_ + hw0 + p2)) * C_;
#pragma unroll
        for (int it = 0; it < 6; ++it) {
            int c0 = cc * 4 + 64 * it;
            f32x4 v;
            v[0] = tile[c0 + 0][p2];
            v[1] = tile[c0 + 1][p2];
            v[2] = tile[c0 + 2][p2];
            v[3] = tile[c0 + 3][p2];
            __builtin_nontemporal_store(v, (f32x4*)(fb + c0));
        }
    }
    {
        int p2 = tid >> 4, cc = tid & 15;
        float inv = s_inv[p2];
        u16* aptr = a_hi + ((size_t)(b * HW_ + hw0 + p2)) * C_;
#pragma unroll
        for (int it = 0; it < 12; ++it) {
            int c0 = 2 * cc + 32 * it;
            u16 h0 = f2bf(tile[c0][p2] * inv);
            u16 h1 = f2bf(tile[c0 + 1][p2] * inv);
            *(u32*)(aptr + c0) = (u32)h0 | ((u32)h1 << 16);
        }
    }
}

// ---------------- K2: bf16 MFMA GEMM ----------------
// DB path: LDS-staged epilogue -> coalesced db (bf16) + dist (fp32 from bf16, NT)
template <bool DB>
__global__ __launch_bounds__(256) void k_gemm(const u16* __restrict__ A,
                                              const u16* __restrict__ Bm,
                                              float* __restrict__ D,
                                              u16* __restrict__ db) {
    __shared__ __align__(16) u16 smem[4][128 * 32];   // As[0..1], Bs[0..1]; 32 KB
    int tid = threadIdx.x;
    int lin = blockIdx.x;
    int swz = (lin & 7) * 392 + (lin >> 3);   // 3136 = 8 * 392, bijective
    int n0 = (swz & 15) * 128;
    int m0 = (swz >> 4) * 128;
    int w = tid >> 6, l = tid & 63;
    int wm = (w >> 1) * 64, wn = (w & 1) * 64;
    int q4 = l >> 4, r15 = l & 15;

    floatx4 acc[4][4];
#pragma unroll
    for (int i = 0; i < 4; ++i)
#pragma unroll
        for (int j = 0; j < 4; ++j) acc[i][j] = (floatx4)0.f;

    int srow = tid >> 2;
    int sp   = tid & 3;
    int fs   = (srow ^ (srow >> 2)) & 3;
    int kk0  = 8 * (sp ^ fs);

#define STAGE(buf, kt)                                                          \
    {                                                                           \
        _Pragma("unroll")                                                       \
        for (int q = 0; q < 2; ++q) {                                           \
            int row = q * 64 + srow;                                            \
            int off = (q * 256 + tid) * 16;                                     \
            gload_lds16(A  + (size_t)(m0 + row) * C_ + (kt) + kk0,              \
                        (char*)smem[buf] + off);                                \
            gload_lds16(Bm + (size_t)(n0 + row) * C_ + (kt) + kk0,              \
                        (char*)smem[2 + (buf)] + off);                          \
        }                                                                       \
    }

    STAGE(0, 0);
    __syncthreads();

    const int slot = (q4 ^ ((r15 ^ (r15 >> 2)) & 3)) << 4;
#pragma unroll 1
    for (int t = 0; t < 12; ++t) {
        int cur = t & 1;
        if (t < 11) STAGE(cur ^ 1, (t + 1) * 32);
        const char* Ab = (const char*)smem[cur];
        const char* Bb = (const char*)smem[2 + cur];
        short8 a[4], b[4];
#pragma unroll
        for (int i = 0; i < 4; ++i) {
            a[i] = *(const short8*)(Ab + (wm + i * 16 + r15) * 64 + slot);
            b[i] = *(const short8*)(Bb + (wn + i * 16 + r15) * 64 + slot);
        }
#pragma unroll
        for (int i = 0; i < 4; ++i)
#pragma unroll
            for (int j = 0; j < 4; ++j)
                acc[i][j] = __builtin_amdgcn_mfma_f32_16x16x32_bf16(a[i], b[j], acc[i][j], 0, 0, 0);
        __syncthreads();
    }

    if (DB) {
        // stage bf16 tile [128 rows][128 cols] in the 32 KB smem, 16B-chunk XOR swizzle
        u16* bft = &smem[0][0];
#pragma unroll
        for (int i = 0; i < 4; ++i) {
#pragma unroll
            for (int j = 0; j < 4; ++j) {
                int col = wn + j * 16 + r15;
#pragma unroll
                for (int r = 0; r < 4; ++r) {
                    int row = wm + i * 16 + q4 * 4 + r;
                    float d = 2.f - 2.f * acc[i][j][r];
                    int c16 = (col >> 3) ^ (row & 15);
                    bft[row * 128 + c16 * 8 + (col & 7)] = f2bf(d);
                }
            }
        }
        __syncthreads();
        // cooperative coalesced stores: 16 lanes cover one 256B bf16 row
        int chunk = tid & 15;
        int rbase = tid >> 4;
#pragma unroll
        for (int rr = 0; rr < 8; ++rr) {
            int row = rbase + 16 * rr;
            u16x8 v = *(const u16x8*)(bft + row * 128 + ((chunk ^ (row & 15)) * 8));
            *(u16x8*)(db + (size_t)(m0 + row) * K_ + n0 + chunk * 8) = v;
            f32x4 f0, f1;
#pragma unroll
            for (int e = 0; e < 4; ++e) { f0[e] = bf2f(v[e]); f1[e] = bf2f(v[4 + e]); }
            float* dp = D + (size_t)(m0 + row) * K_ + n0 + chunk * 8;
            __builtin_nontemporal_store(f0, (f32x4*)dp);
            __builtin_nontemporal_store(f1, (f32x4*)(dp + 4));
        }
    } else {
#pragma unroll
        for (int i = 0; i < 4; ++i) {
            int gm = m0 + wm + i * 16 + q4 * 4;
#pragma unroll
            for (int j = 0; j < 4; ++j) {
                int gn = n0 + wn + j * 16 + r15;
#pragma unroll
                for (int r = 0; r < 4; ++r)
                    D[(size_t)(gm + r) * K_ + gn] = 2.f - 2.f * acc[i][j][r];
            }
        }
    }
#undef STAGE
}

// ---------------- K3: streaming row stats from bf16 shadow ----------------
__global__ __launch_bounds__(256) void k_stats_b(const u16* __restrict__ db,
                                                 float2* __restrict__ srow) {
    int row = blockIdx.x * 4 + (threadIdx.x >> 6);
    int l   = threadIdx.x & 63;
    const u16* dr = db + (size_t)row * K_;
    float es = 0.f, dm = 3.4e38f;
#pragma unroll
    for (int i = 0; i < 4; ++i) {
        u16x8 v = *(const u16x8*)(dr + l * 8 + 512 * i);
#pragma unroll
        for (int e = 0; e < 8; ++e) {
            float d = bf2f(v[e]);
            es += __expf(-10.f * d);
            dm = fminf(dm, d);
        }
    }
#pragma unroll
    for (int off = 32; off; off >>= 1) {
        es += __shfl_xor(es, off, 64);
        dm = fminf(dm, __shfl_xor(dm, off, 64));
    }
    if (l == 0) {
        float2 st;
        st.x = 1.f / es;
        st.y = dm + MARGIN;
        srow[row] = st;
    }
}

// fp32 fallback
__global__ __launch_bounds__(256) void k_stats_f(const float* __restrict__ D,
                                                 float2* __restrict__ srow) {
    int row = blockIdx.x * 4 + (threadIdx.x >> 6);
    int l   = threadIdx.x & 63;
    const float* dr = D + (size_t)row * K_;
    float es = 0.f, dm = 3.4e38f;
#pragma unroll
    for (int i = 0; i < 8; ++i) {
        float4 v = *(const float4*)(dr + l * 4 + 256 * i);
        es += __expf(-10.f * v.x) + __expf(-10.f * v.y)
            + __expf(-10.f * v.z) + __expf(-10.f * v.w);
        dm = fminf(dm, fminf(fminf(v.x, v.y), fminf(v.z, v.w)));
    }
#pragma unroll
    for (int off = 32; off; off >>= 1) {
        es += __shfl_xor(es, off, 64);
        dm = fminf(dm, __shfl_xor(dm, off, 64));
    }
    if (l == 0) {
        float2 st;
        st.x = 1.f / es;
        st.y = dm + MARGIN;
        srow[row] = st;
    }
}

// ---------------- K4: assignment + candidate collection (bf16 shadow) ----------------
__global__ __launch_bounds__(256) void k_post_b(const u16* __restrict__ db,
                                                const float2* __restrict__ srow,
                                                u32* __restrict__ Qi,
                                                float* __restrict__ asg) {
    __shared__ float tbuf[64][113];
    __shared__ float s_inv[PPX], s_thr[PPX];
    __shared__ int   s_cnt[PPX];
    __shared__ int   s_cand[PPX][16];
    int tile = blockIdx.x;
    int kc   = blockIdx.y;
    int b    = tile / 7;
    int hw0  = (tile - b * 7) * PPX;
    int n0   = b * HW_ + hw0;
    int tid  = threadIdx.x;

    if (tid < PPX) {
        float2 st = srow[n0 + tid];
        s_inv[tid] = st.x;
        s_thr[tid] = st.y;
        s_cnt[tid] = 0;
    }
    __syncthreads();

    int r16 = tid >> 4, c4 = (tid & 15) * 4;
    int px = tid & 127, kg = tid >> 7;
#pragma unroll 1
    for (int ch = 0; ch < 8; ++ch) {
        int k0 = kc * 512 + ch * 64;
#pragma unroll
        for (int rr = 0; rr < 7; ++rr) {
            int row = r16 + 16 * rr;
            u16x4 dv = *(const u16x4*)(db + (size_t)(n0 + row) * K_ + k0 + c4);
            float inv = s_inv[row], thr = s_thr[row];
#pragma unroll
            for (int cc = 0; cc < 4; ++cc) {
                float d = bf2f(dv[cc]);
                tbuf[c4 + cc][row] = __expf(-10.f * d) * inv;
                if (d <= thr) {
                    int idx = atomicAdd(&s_cnt[row], 1);
                    if (idx < 16) s_cand[row][idx] = k0 + c4 + cc;
                }
            }
        }
        __syncthreads();
        if (px < PPX) {
            size_t base = ((size_t)(b * K_ + k0 + kg * 32)) * HW_ + hw0 + px;
#pragma unroll
            for (int ki = 0; ki < 32; ++ki)
                __builtin_nontemporal_store(tbuf[kg * 32 + ki][px],
                                            asg + base + (size_t)ki * HW_);
        }
        __syncthreads();
    }

    if (tid < PPX) {
        int cnt = s_cnt[tid];
        cnt = cnt > 16 ? 16 : cnt;
        Qi[qslot(b, kc * 17, hw0 + tid)] = (u32)cnt;
        for (int ci = 0; ci < cnt; ++ci)
            Qi[qslot(b, kc * 17 + 1 + ci, hw0 + tid)] = (u32)s_cand[tid][ci];
    }
}

// fp32 fallback
__global__ __launch_bounds__(256) void k_post_f(const float* __restrict__ D,
                                                const float2* __restrict__ srow,
                                                u32* __restrict__ Qi,
                                                float* __restrict__ asg) {
    __shared__ float tbuf[64][113];
    __shared__ float s_inv[PPX], s_thr[PPX];
    __shared__ int   s_cnt[PPX];
    __shared__ int   s_cand[PPX][16];
    int tile = blockIdx.x;
    int kc   = blockIdx.y;
    int b    = tile / 7;
    int hw0  = (tile - b * 7) * PPX;
    int n0   = b * HW_ + hw0;
    int tid  = threadIdx.x;

    if (tid < PPX) {
        float2 st = srow[n0 + tid];
        s_inv[tid] = st.x;
        s_thr[tid] = st.y;
        s_cnt[tid] = 0;
    }
    __syncthreads();

    int r16 = tid >> 4, c4 = (tid & 15) * 4;
    int px = tid & 127, kg = tid >> 7;
#pragma unroll 1
    for (int ch = 0; ch < 8; ++ch) {
        int k0 = kc * 512 + ch * 64;
#pragma unroll
        for (int rr = 0; rr < 7; ++rr) {
            int row = r16 + 16 * rr;
            f32x4 dv = __builtin_nontemporal_load(
                (const f32x4*)(D + (size_t)(n0 + row) * K_ + k0 + c4));
            float inv = s_inv[row], thr = s_thr[row];
#pragma unroll
            for (int cc = 0; cc < 4; ++cc) {
                float d = dv[cc];
                tbuf[c4 + cc][row] = __expf(-10.f * d) * inv;
                if (d <= thr) {
                    int idx = atomicAdd(&s_cnt[row], 1);
                    if (idx < 16) s_cand[row][idx] = k0 + c4 + cc;
                }
            }
        }
        __syncthreads();
        if (px < PPX) {
            size_t base = ((size_t)(b * K_ + k0 + kg * 32)) * HW_ + hw0 + px;
#pragma unroll
            for (int ki = 0; ki < 32; ++ki)
                __builtin_nontemporal_store(tbuf[kg * 32 + ki][px],
                                            asg + base + (size_t)ki * HW_);
        }
        __syncthreads();
    }

    if (tid < PPX) {
        int cnt = s_cnt[tid];
        cnt = cnt > 16 ? 16 : cnt;
        Qi[qslot(b, kc * 17, hw0 + tid)] = (u32)cnt;
        for (int ci = 0; ci < cnt; ++ci)
            Qi[qslot(b, kc * 17 + 1 + ci, hw0 + tid)] = (u32)s_cand[tid][ci];
    }
}

// ---------------- K5: merge candidates, exact recheck, q gather ----------------
__global__ __launch_bounds__(256) void k_q(const u32* __restrict__ Qi,
                                           const float* __restrict__ codeN,
                                           const float* __restrict__ invN,
                                           const float* __restrict__ f_in,
                                           float* __restrict__ qOut) {
    __shared__ int s_amin[PPX], s_cnt[PPX];
    __shared__ int s_cand[PPX][64];
    int tile = blockIdx.x;
    int b    = tile / 7;
    int hw0  = (tile - b * 7) * PPX;
    int npix = b * HW_ + hw0;
    int tid  = threadIdx.x;

    if (tid < PPX) {
        int total = 0;
#pragma unroll
        for (int kc = 0; kc < 4; ++kc) {
            int cnt = (int)Qi[qslot(b, kc * 17, hw0 + tid)];
            for (int ci = 0; ci < cnt; ++ci)
                s_cand[tid][total++] = (int)Qi[qslot(b, kc * 17 + 1 + ci, hw0 + tid)];
        }
        s_cnt[tid]  = total;
        s_amin[tid] = s_cand[tid][0];
    }
    __syncthreads();

    int w = tid >> 6, l = tid & 63;
#pragma unroll 1
    for (int r = w; r < PPX; r += 4) {
        int cnt = s_cnt[r];
        if (cnt < 2) continue;
        float ivn = invN[npix + r];
        float fv[6];
        const float* frow = f_in + (size_t)(npix + r) * C_;
#pragma unroll
        for (int ii = 0; ii < 6; ++ii)
            fv[ii] = frow[l + 64 * ii] * ivn;
        float dbest = 3.4e38f;
        int   kbest = -1;
        for (int ci = 0; ci < cnt; ++ci) {
            int k = s_cand[r][ci];
            float dt = 0.f;
            const float* cr = codeN + (size_t)k * C_;
#pragma unroll
            for (int ii = 0; ii < 6; ++ii) dt = fmaf(fv[ii], cr[l + 64 * ii], dt);
#pragma unroll
            for (int off = 1; off < 64; off <<= 1) dt += __shfl_xor(dt, off, 64);
            float dex = 2.f - 2.f * dt;
            if (kbest < 0 || dex < dbest || (dex == dbest && k < kbest)) { dbest = dex; kbest = k; }
        }
        if (l == 0) s_amin[r] = kbest;
    }
    __syncthreads();

    int px = tid & 127, kg = tid >> 7;
    if (px < PPX) {
        const float* cr = codeN + (size_t)s_amin[px] * C_ + kg * 192;
        size_t qb = ((size_t)b * C_ + kg * 192) * HW_ + hw0 + px;
#pragma unroll 1
        for (int c4 = 0; c4 < 48; ++c4) {
            float4 v = *(const float4*)(cr + 4 * c4);
            __builtin_nontemporal_store(v.x, qOut + qb + (size_t)(4 * c4 + 0) * HW_);
            __builtin_nontemporal_store(v.y, qOut + qb + (size_t)(4 * c4 + 1) * HW_);
            __builtin_nontemporal_store(v.z, qOut + qb + (size_t)(4 * c4 + 2) * HW_);
            __builtin_nontemporal_store(v.w, qOut + qb + (size_t)(4 * c4 + 3) * HW_);
        }
    }
}

extern "C" void kernel_launch(void* const* d_in, const int* in_sizes, int n_in,
                              void* d_out, int out_size, void* d_ws, size_t ws_size,
                              hipStream_t stream) {
    const float* feat = (const float*)d_in[0];
    const float* cb   = (const float*)d_in[1];
    float* out    = (float*)d_out;
    float* f_out  = out + OFF_F;
    float* q_out  = out + OFF_Q;     // holds candidate scratch until k_q overwrites
    float* asg    = out + OFF_ASG;   // first 20.8 MB holds a_hi/b_hi until k_post
    float* dist   = out + OFF_DIST;

    u16* a_hi = (u16*)asg;
    u16* b_hi = a_hi + (size_t)N_ * C_;
    u32* Qi   = (u32*)q_out;

    const size_t DB_BYTES = (size_t)N_ * K_ * 2;          // 102,760,448
    bool big = ws_size >= DB_BYTES + 3145728 + 100352 + 200704;

    if (big) {
        u16*    db     = (u16*)d_ws;
        float*  code_n = (float*)((char*)d_ws + DB_BYTES);
        float*  inv_n  = (float*)((char*)d_ws + DB_BYTES + 3145728);
        float2* srow   = (float2*)((char*)d_ws + DB_BYTES + 3145728 + 100352);

        k_prep<<<2080, 256, 0, stream>>>(feat, cb, f_out, inv_n, a_hi, code_n, b_hi);
        k_gemm<true><<<3136, 256, 0, stream>>>(a_hi, b_hi, dist, db);
        k_stats_b<<<N_ / 4, 256, 0, stream>>>(db, srow);
        k_post_b<<<dim3(224, 4), 256, 0, stream>>>(db, srow, Qi, asg);
        k_q<<<224, 256, 0, stream>>>(Qi, code_n, inv_n, f_out, q_out);
    } else {
        float*  code_n = (float*)d_ws;
        float*  inv_n  = (float*)((char*)d_ws + 3145728);
        float2* srow   = (float2*)((char*)d_ws + 3246080);

        k_prep<<<2080, 256, 0, stream>>>(feat, cb, f_out, inv_n, a_hi, code_n, b_hi);
        k_gemm<false><<<3136, 256, 0, stream>>>(a_hi, b_hi, dist, nullptr);
        k_stats_f<<<N_ / 4, 256, 0, stream>>>(dist, srow);
        k_post_f<<<dim3(224, 4), 256, 0, stream>>>(dist, srow, Qi, asg);
        k_q<<<224, 256, 0, stream>>>(Qi, code_n, inv_n, f_out, q_out);
    }
}

// Round 11
// 261.189 us; speedup vs baseline: 1.2301x; 1.0622x over previous
//
#include <hip/hip_runtime.h>

#define B_  32
#define C_  384
#define HW_ 784
#define N_  25088   // B_*HW_
#define K_  2048
#define PPX 112     // pixels per post/q block; 7*112=784

#define OFF_F    0
#define OFF_Q    9633792
#define OFF_ASG  19267584
#define OFF_DIST 70647808

#define MARGIN 0.02f

typedef unsigned short u16;
typedef unsigned int u32;
typedef __attribute__((ext_vector_type(8))) short short8;
typedef __attribute__((ext_vector_type(4))) float floatx4;
typedef __attribute__((ext_vector_type(4))) float f32x4;
typedef __attribute__((ext_vector_type(4))) u16 u16x4;
typedef __attribute__((ext_vector_type(8))) u16 u16x8;

static __device__ __forceinline__ u16 f2bf(float x) {
    u32 u = __builtin_bit_cast(u32, x);
    u32 r = (u + 0x7FFFu + ((u >> 16) & 1u)) >> 16;
    return (u16)r;
}
static __device__ __forceinline__ float bf2f(u16 v) {
    return __builtin_bit_cast(float, (u32)v << 16);
}

static __device__ __forceinline__ void gload_lds16(const void* g, void* l) {
    __builtin_amdgcn_global_load_lds(
        (const __attribute__((address_space(1))) unsigned int*)g,
        (__attribute__((address_space(3))) unsigned int*)l,
        16, 0, 0);
}

// fallback-path scratch slots in the q output region
static __device__ __forceinline__ size_t qslot(int b, int s, int hw) {
    return ((size_t)b * C_ + s) * HW_ + hw;
}

// ---------------- K1: feat -> f, inv_n, a_hi  AND  codebook -> code_n, b_hi ----------------
__global__ __launch_bounds__(256) void k_prep(const float* __restrict__ feat,
                                              const float* __restrict__ cb,
                                              float* __restrict__ f_out,
                                              float* __restrict__ inv_n,
                                              u16* __restrict__ a_hi,
                                              float* __restrict__ code_n,
                                              u16* __restrict__ b_hi) {
    int tid = threadIdx.x;
    if (blockIdx.x >= 1568) {
        int row  = (blockIdx.x - 1568) * 4 + (tid >> 6);
        int lane = tid & 63;
        const float* src = cb + (size_t)row * C_;
        float v[6];
        float ss = 0.f;
#pragma unroll
        for (int i = 0; i < 6; ++i) { v[i] = src[lane + 64 * i]; ss += v[i] * v[i]; }
#pragma unroll
        for (int off = 32; off; off >>= 1) ss += __shfl_xor(ss, off, 64);
        float inv = 1.f / fmaxf(sqrtf(ss), 1e-12f);
#pragma unroll
        for (int i = 0; i < 6; ++i) {
            float vn = v[i] * inv;
            code_n[(size_t)row * C_ + lane + 64 * i] = vn;
            b_hi  [(size_t)row * C_ + lane + 64 * i] = f2bf(vn);
        }
        return;
    }
    __shared__ float tile[C_][17];
    __shared__ float red[16][17];
    __shared__ float s_inv[16];
    int b   = blockIdx.x / 49;
    int hw0 = (blockIdx.x - b * 49) * 16;
    int px  = tid & 15, cq = tid >> 4;

#pragma unroll
    for (int it = 0; it < 24; ++it) {
        int c = cq + 16 * it;
        tile[c][px] = feat[((size_t)(b * C_ + c)) * HW_ + hw0 + px];
    }
    __syncthreads();
    float ss = 0.f;
#pragma unroll
    for (int q = 0; q < 24; ++q) {
        float v = tile[cq + 16 * q][px];
        ss = fmaf(v, v, ss);
    }
    red[cq][px] = ss;
    __syncthreads();
    if (tid < 16) {
        float tot = 0.f;
#pragma unroll
        for (int p = 0; p < 16; ++p) tot += red[p][tid];
        float inv = 1.f / fmaxf(sqrtf(tot), 1e-12f);
        s_inv[tid] = inv;
        inv_n[(size_t)b * HW_ + hw0 + tid] = inv;
    }
    __syncthreads();

    {
        int p2 = tid >> 4, cc = tid & 15;
        float* fb = f_out + ((size_t)(b * HW_ + hw0 + p2)) * C_;
#pragma unroll
        for (int it = 0; it < 6; ++it) {
            int c0 = cc * 4 + 64 * it;
            f32x4 v;
            v[0] = tile[c0 + 0][p2];
            v[1] = tile[c0 + 1][p2];
            v[2] = tile[c0 + 2][p2];
            v[3] = tile[c0 + 3][p2];
            __builtin_nontemporal_store(v, (f32x4*)(fb + c0));
        }
    }
    {
        int p2 = tid >> 4, cc = tid & 15;
        float inv = s_inv[p2];
        u16* aptr = a_hi + ((size_t)(b * HW_ + hw0 + p2)) * C_;
#pragma unroll
        for (int it = 0; it < 12; ++it) {
            int c0 = 2 * cc + 32 * it;
            u16 h0 = f2bf(tile[c0][p2] * inv);
            u16 h1 = f2bf(tile[c0 + 1][p2] * inv);
            *(u32*)(aptr + c0) = (u32)h0 | ((u32)h1 << 16);
        }
    }
}

// ---------------- K2: bf16 MFMA GEMM ----------------
// DB path: write ONLY the bf16 shadow (fp32 dist is expanded later in k_post_b)
template <bool DB>
__global__ __launch_bounds__(256) void k_gemm(const u16* __restrict__ A,
                                              const u16* __restrict__ Bm,
                                              float* __restrict__ D,
                                              u16* __restrict__ db) {
    __shared__ u16 As[2][128 * 32];
    __shared__ u16 Bs[2][128 * 32];
    int tid = threadIdx.x;
    int lin = blockIdx.x;
    int swz = (lin & 7) * 392 + (lin >> 3);   // 3136 = 8 * 392, bijective
    int n0 = (swz & 15) * 128;
    int m0 = (swz >> 4) * 128;
    int w = tid >> 6, l = tid & 63;
    int wm = (w >> 1) * 64, wn = (w & 1) * 64;
    int q4 = l >> 4, r15 = l & 15;

    floatx4 acc[4][4];
#pragma unroll
    for (int i = 0; i < 4; ++i)
#pragma unroll
        for (int j = 0; j < 4; ++j) acc[i][j] = (floatx4)0.f;

    int srow = tid >> 2;
    int sp   = tid & 3;
    int fs   = (srow ^ (srow >> 2)) & 3;
    int kk0  = 8 * (sp ^ fs);

#define STAGE(buf, kt)                                                          \
    {                                                                           \
        _Pragma("unroll")                                                       \
        for (int q = 0; q < 2; ++q) {                                           \
            int row = q * 64 + srow;                                            \
            int off = (q * 256 + tid) * 16;                                     \
            gload_lds16(A  + (size_t)(m0 + row) * C_ + (kt) + kk0,              \
                        (char*)As[buf] + off);                                  \
            gload_lds16(Bm + (size_t)(n0 + row) * C_ + (kt) + kk0,              \
                        (char*)Bs[buf] + off);                                  \
        }                                                                       \
    }

    STAGE(0, 0);
    __syncthreads();

    const int slot = (q4 ^ ((r15 ^ (r15 >> 2)) & 3)) << 4;
#pragma unroll 1
    for (int t = 0; t < 12; ++t) {
        int cur = t & 1;
        if (t < 11) STAGE(cur ^ 1, (t + 1) * 32);
        const char* Ab = (const char*)As[cur];
        const char* Bb = (const char*)Bs[cur];
        short8 a[4], b[4];
#pragma unroll
        for (int i = 0; i < 4; ++i) {
            a[i] = *(const short8*)(Ab + (wm + i * 16 + r15) * 64 + slot);
            b[i] = *(const short8*)(Bb + (wn + i * 16 + r15) * 64 + slot);
        }
#pragma unroll
        for (int i = 0; i < 4; ++i)
#pragma unroll
            for (int j = 0; j < 4; ++j)
                acc[i][j] = __builtin_amdgcn_mfma_f32_16x16x32_bf16(a[i], b[j], acc[i][j], 0, 0, 0);
        __syncthreads();
    }

#pragma unroll
    for (int i = 0; i < 4; ++i) {
        int gm = m0 + wm + i * 16 + q4 * 4;
#pragma unroll
        for (int j = 0; j < 4; ++j) {
            int gn = n0 + wn + j * 16 + r15;
#pragma unroll
            for (int r = 0; r < 4; ++r) {
                float d = 2.f - 2.f * acc[i][j][r];
                if (DB) {
                    db[(size_t)(gm + r) * K_ + gn] = f2bf(d);
                } else {
                    D[(size_t)(gm + r) * K_ + gn] = d;
                }
            }
        }
    }
#undef STAGE
}

// ---------------- K3: streaming row stats from bf16 shadow ----------------
__global__ __launch_bounds__(256) void k_stats_b(const u16* __restrict__ db,
                                                 float2* __restrict__ srow) {
    int row = blockIdx.x * 4 + (threadIdx.x >> 6);
    int l   = threadIdx.x & 63;
    const u16* dr = db + (size_t)row * K_;
    float es = 0.f, dm = 3.4e38f;
#pragma unroll
    for (int i = 0; i < 4; ++i) {
        u16x8 v = *(const u16x8*)(dr + l * 8 + 512 * i);
#pragma unroll
        for (int e = 0; e < 8; ++e) {
            float d = bf2f(v[e]);
            es += __expf(-10.f * d);
            dm = fminf(dm, d);
        }
    }
#pragma unroll
    for (int off = 32; off; off >>= 1) {
        es += __shfl_xor(es, off, 64);
        dm = fminf(dm, __shfl_xor(dm, off, 64));
    }
    if (l == 0) {
        float2 st;
        st.x = 1.f / es;
        st.y = dm + MARGIN;
        srow[row] = st;
    }
}

// fp32 fallback
__global__ __launch_bounds__(256) void k_stats_f(const float* __restrict__ D,
                                                 float2* __restrict__ srow) {
    int row = blockIdx.x * 4 + (threadIdx.x >> 6);
    int l   = threadIdx.x & 63;
    const float* dr = D + (size_t)row * K_;
    float es = 0.f, dm = 3.4e38f;
#pragma unroll
    for (int i = 0; i < 8; ++i) {
        float4 v = *(const float4*)(dr + l * 4 + 256 * i);
        es += __expf(-10.f * v.x) + __expf(-10.f * v.y)
            + __expf(-10.f * v.z) + __expf(-10.f * v.w);
        dm = fminf(dm, fminf(fminf(v.x, v.y), fminf(v.z, v.w)));
    }
#pragma unroll
    for (int off = 32; off; off >>= 1) {
        es += __shfl_xor(es, off, 64);
        dm = fminf(dm, __shfl_xor(dm, off, 64));
    }
    if (l == 0) {
        float2 st;
        st.x = 1.f / es;
        st.y = dm + MARGIN;
        srow[row] = st;
    }
}

// ---------------- K4: assignment + dist expand + candidate collection (bf16 shadow) ----------------
__global__ __launch_bounds__(256) void k_post_b(const u16* __restrict__ db,
                                                const float2* __restrict__ srow,
                                                u32* __restrict__ Qi,
                                                float* __restrict__ asg,
                                                float* __restrict__ D) {
    __shared__ float tbuf[64][113];
    __shared__ float s_inv[PPX], s_thr[PPX];
    __shared__ int   s_cnt[PPX];
    __shared__ int   s_cand[PPX][16];
    int tile = blockIdx.x;
    int kc   = blockIdx.y;
    int b    = tile / 7;
    int hw0  = (tile - b * 7) * PPX;
    int n0   = b * HW_ + hw0;
    int tid  = threadIdx.x;

    if (tid < PPX) {
        float2 st = srow[n0 + tid];
        s_inv[tid] = st.x;
        s_thr[tid] = st.y;
        s_cnt[tid] = 0;
    }
    __syncthreads();

    int r16 = tid >> 4, c4 = (tid & 15) * 4;
    int px = tid & 127, kg = tid >> 7;
#pragma unroll 1
    for (int ch = 0; ch < 8; ++ch) {
        int k0 = kc * 512 + ch * 64;
#pragma unroll
        for (int rr = 0; rr < 7; ++rr) {
            int row = r16 + 16 * rr;
            u16x4 dv = *(const u16x4*)(db + (size_t)(n0 + row) * K_ + k0 + c4);
            float inv = s_inv[row], thr = s_thr[row];
            f32x4 df;
#pragma unroll
            for (int cc = 0; cc < 4; ++cc) {
                float d = bf2f(dv[cc]);
                df[cc] = d;
                tbuf[c4 + cc][row] = __expf(-10.f * d) * inv;
                if (d <= thr) {
                    int idx = atomicAdd(&s_cnt[row], 1);
                    if (idx < 16) s_cand[row][idx] = k0 + c4 + cc;
                }
            }
            // dist fp32 expand: 16B/lane, 256B per 16-lane group, NT
            __builtin_nontemporal_store(df,
                (f32x4*)(D + (size_t)(n0 + row) * K_ + k0 + c4));
        }
        __syncthreads();
        if (px < PPX) {
            size_t base = ((size_t)(b * K_ + k0 + kg * 32)) * HW_ + hw0 + px;
#pragma unroll
            for (int ki = 0; ki < 32; ++ki)
                __builtin_nontemporal_store(tbuf[kg * 32 + ki][px],
                                            asg + base + (size_t)ki * HW_);
        }
        __syncthreads();
    }

    if (tid < PPX) {
        int cnt = s_cnt[tid];
        cnt = cnt > 16 ? 16 : cnt;
        Qi[qslot(b, kc * 17, hw0 + tid)] = (u32)cnt;
        for (int ci = 0; ci < cnt; ++ci)
            Qi[qslot(b, kc * 17 + 1 + ci, hw0 + tid)] = (u32)s_cand[tid][ci];
    }
}

// fp32 fallback
__global__ __launch_bounds__(256) void k_post_f(const float* __restrict__ D,
                                                const float2* __restrict__ srow,
                                                u32* __restrict__ Qi,
                                                float* __restrict__ asg) {
    __shared__ float tbuf[64][113];
    __shared__ float s_inv[PPX], s_thr[PPX];
    __shared__ int   s_cnt[PPX];
    __shared__ int   s_cand[PPX][16];
    int tile = blockIdx.x;
    int kc   = blockIdx.y;
    int b    = tile / 7;
    int hw0  = (tile - b * 7) * PPX;
    int n0   = b * HW_ + hw0;
    int tid  = threadIdx.x;

    if (tid < PPX) {
        float2 st = srow[n0 + tid];
        s_inv[tid] = st.x;
        s_thr[tid] = st.y;
        s_cnt[tid] = 0;
    }
    __syncthreads();

    int r16 = tid >> 4, c4 = (tid & 15) * 4;
    int px = tid & 127, kg = tid >> 7;
#pragma unroll 1
    for (int ch = 0; ch < 8; ++ch) {
        int k0 = kc * 512 + ch * 64;
#pragma unroll
        for (int rr = 0; rr < 7; ++rr) {
            int row = r16 + 16 * rr;
            f32x4 dv = __builtin_nontemporal_load(
                (const f32x4*)(D + (size_t)(n0 + row) * K_ + k0 + c4));
            float inv = s_inv[row], thr = s_thr[row];
#pragma unroll
            for (int cc = 0; cc < 4; ++cc) {
                float d = dv[cc];
                tbuf[c4 + cc][row] = __expf(-10.f * d) * inv;
                if (d <= thr) {
                    int idx = atomicAdd(&s_cnt[row], 1);
                    if (idx < 16) s_cand[row][idx] = k0 + c4 + cc;
                }
            }
        }
        __syncthreads();
        if (px < PPX) {
            size_t base = ((size_t)(b * K_ + k0 + kg * 32)) * HW_ + hw0 + px;
#pragma unroll
            for (int ki = 0; ki < 32; ++ki)
                __builtin_nontemporal_store(tbuf[kg * 32 + ki][px],
                                            asg + base + (size_t)ki * HW_);
        }
        __syncthreads();
    }

    if (tid < PPX) {
        int cnt = s_cnt[tid];
        cnt = cnt > 16 ? 16 : cnt;
        Qi[qslot(b, kc * 17, hw0 + tid)] = (u32)cnt;
        for (int ci = 0; ci < cnt; ++ci)
            Qi[qslot(b, kc * 17 + 1 + ci, hw0 + tid)] = (u32)s_cand[tid][ci];
    }
}

// ---------------- K5: merge candidates, exact recheck, q gather ----------------
__global__ __launch_bounds__(256) void k_q(const u32* __restrict__ Qi,
                                           const float* __restrict__ codeN,
                                           const float* __restrict__ invN,
                                           const float* __restrict__ f_in,
                                           float* __restrict__ qOut) {
    __shared__ int s_amin[PPX], s_cnt[PPX];
    __shared__ int s_cand[PPX][64];
    int tile = blockIdx.x;
    int b    = tile / 7;
    int hw0  = (tile - b * 7) * PPX;
    int npix = b * HW_ + hw0;
    int tid  = threadIdx.x;

    if (tid < PPX) {
        int total = 0;
#pragma unroll
        for (int kc = 0; kc < 4; ++kc) {
            int cnt = (int)Qi[qslot(b, kc * 17, hw0 + tid)];
            for (int ci = 0; ci < cnt; ++ci)
                s_cand[tid][total++] = (int)Qi[qslot(b, kc * 17 + 1 + ci, hw0 + tid)];
        }
        s_cnt[tid]  = total;
        s_amin[tid] = s_cand[tid][0];
    }
    __syncthreads();

    int w = tid >> 6, l = tid & 63;
#pragma unroll 1
    for (int r = w; r < PPX; r += 4) {
        int cnt = s_cnt[r];
        if (cnt < 2) continue;
        float ivn = invN[npix + r];
        float fv[6];
        const float* frow = f_in + (size_t)(npix + r) * C_;
#pragma unroll
        for (int ii = 0; ii < 6; ++ii)
            fv[ii] = frow[l + 64 * ii] * ivn;
        float dbest = 3.4e38f;
        int   kbest = -1;
        for (int ci = 0; ci < cnt; ++ci) {
            int k = s_cand[r][ci];
            float dt = 0.f;
            const float* cr = codeN + (size_t)k * C_;
#pragma unroll
            for (int ii = 0; ii < 6; ++ii) dt = fmaf(fv[ii], cr[l + 64 * ii], dt);
#pragma unroll
            for (int off = 1; off < 64; off <<= 1) dt += __shfl_xor(dt, off, 64);
            float dex = 2.f - 2.f * dt;
            if (kbest < 0 || dex < dbest || (dex == dbest && k < kbest)) { dbest = dex; kbest = k; }
        }
        if (l == 0) s_amin[r] = kbest;
    }
    __syncthreads();

    int px = tid & 127, kg = tid >> 7;
    if (px < PPX) {
        const float* cr = codeN + (size_t)s_amin[px] * C_ + kg * 192;
        size_t qb = ((size_t)b * C_ + kg * 192) * HW_ + hw0 + px;
#pragma unroll 1
        for (int c4 = 0; c4 < 48; ++c4) {
            float4 v = *(const float4*)(cr + 4 * c4);
            __builtin_nontemporal_store(v.x, qOut + qb + (size_t)(4 * c4 + 0) * HW_);
            __builtin_nontemporal_store(v.y, qOut + qb + (size_t)(4 * c4 + 1) * HW_);
            __builtin_nontemporal_store(v.z, qOut + qb + (size_t)(4 * c4 + 2) * HW_);
            __builtin_nontemporal_store(v.w, qOut + qb + (size_t)(4 * c4 + 3) * HW_);
        }
    }
}

extern "C" void kernel_launch(void* const* d_in, const int* in_sizes, int n_in,
                              void* d_out, int out_size, void* d_ws, size_t ws_size,
                              hipStream_t stream) {
    const float* feat = (const float*)d_in[0];
    const float* cb   = (const float*)d_in[1];
    float* out    = (float*)d_out;
    float* f_out  = out + OFF_F;
    float* q_out  = out + OFF_Q;     // holds candidate scratch until k_q overwrites
    float* asg    = out + OFF_ASG;   // first 20.8 MB holds a_hi/b_hi until k_post
    float* dist   = out + OFF_DIST;

    u16* a_hi = (u16*)asg;
    u16* b_hi = a_hi + (size_t)N_ * C_;
    u32* Qi   = (u32*)q_out;

    const size_t DB_BYTES = (size_t)N_ * K_ * 2;          // 102,760,448
    bool big = ws_size >= DB_BYTES + 3145728 + 100352 + 200704;

    if (big) {
        u16*    db     = (u16*)d_ws;
        float*  code_n = (float*)((char*)d_ws + DB_BYTES);
        float*  inv_n  = (float*)((char*)d_ws + DB_BYTES + 3145728);
        float2* srow   = (float2*)((char*)d_ws + DB_BYTES + 3145728 + 100352);

        k_prep<<<2080, 256, 0, stream>>>(feat, cb, f_out, inv_n, a_hi, code_n, b_hi);
        k_gemm<true><<<3136, 256, 0, stream>>>(a_hi, b_hi, dist, db);
        k_stats_b<<<N_ / 4, 256, 0, stream>>>(db, srow);
        k_post_b<<<dim3(224, 4), 256, 0, stream>>>(db, srow, Qi, asg, dist);
        k_q<<<224, 256, 0, stream>>>(Qi, code_n, inv_n, f_out, q_out);
    } else {
        float*  code_n = (float*)d_ws;
        float*  inv_n  = (float*)((char*)d_ws + 3145728);
        float2* srow   = (float2*)((char*)d_ws + 3246080);

        k_prep<<<2080, 256, 0, stream>>>(feat, cb, f_out, inv_n, a_hi, code_n, b_hi);
        k_gemm<false><<<3136, 256, 0, stream>>>(a_hi, b_hi, dist, nullptr);
        k_stats_f<<<N_ / 4, 256, 0, stream>>>(dist, srow);
        k_post_f<<<dim3(224, 4), 256, 0, stream>>>(dist, srow, Qi, asg);
        k_q<<<224, 256, 0, stream>>>(Qi, code_n, inv_n, f_out, q_out);
    }
}

// Round 12
// 247.143 us; speedup vs baseline: 1.3000x; 1.0568x over previous
//
#include <hip/hip_runtime.h>

#define B_  32
#define C_  384
#define HW_ 784
#define N_  25088   // B_*HW_
#define K_  2048
#define PPX 112     // pixels per post/q block; 7*112=784

#define OFF_F    0
#define OFF_Q    9633792
#define OFF_ASG  19267584
#define OFF_DIST 70647808

#define MARGIN 0.02f

typedef unsigned short u16;
typedef unsigned int u32;
typedef __attribute__((ext_vector_type(8))) short short8;
typedef __attribute__((ext_vector_type(4))) float floatx4;
typedef __attribute__((ext_vector_type(4))) float f32x4;
typedef __attribute__((ext_vector_type(4))) u16 u16x4;
typedef __attribute__((ext_vector_type(8))) u16 u16x8;

static __device__ __forceinline__ u16 f2bf(float x) {
    u32 u = __builtin_bit_cast(u32, x);
    u32 r = (u + 0x7FFFu + ((u >> 16) & 1u)) >> 16;
    return (u16)r;
}
static __device__ __forceinline__ float bf2f(u16 v) {
    return __builtin_bit_cast(float, (u32)v << 16);
}

static __device__ __forceinline__ void gload_lds16(const void* g, void* l) {
    __builtin_amdgcn_global_load_lds(
        (const __attribute__((address_space(1))) unsigned int*)g,
        (__attribute__((address_space(3))) unsigned int*)l,
        16, 0, 0);
}

// fallback-path scratch slots in the q output region
static __device__ __forceinline__ size_t qslot(int b, int s, int hw) {
    return ((size_t)b * C_ + s) * HW_ + hw;
}

// ---------------- K1: feat -> f, inv_n, a_hi  AND  codebook -> code_n, b_hi ----------------
__global__ __launch_bounds__(256) void k_prep(const float* __restrict__ feat,
                                              const float* __restrict__ cb,
                                              float* __restrict__ f_out,
                                              float* __restrict__ inv_n,
                                              u16* __restrict__ a_hi,
                                              float* __restrict__ code_n,
                                              u16* __restrict__ b_hi) {
    int tid = threadIdx.x;
    if (blockIdx.x >= 1568) {
        int row  = (blockIdx.x - 1568) * 4 + (tid >> 6);
        int lane = tid & 63;
        const float* src = cb + (size_t)row * C_;
        float v[6];
        float ss = 0.f;
#pragma unroll
        for (int i = 0; i < 6; ++i) { v[i] = src[lane + 64 * i]; ss += v[i] * v[i]; }
#pragma unroll
        for (int off = 32; off; off >>= 1) ss += __shfl_xor(ss, off, 64);
        float inv = 1.f / fmaxf(sqrtf(ss), 1e-12f);
#pragma unroll
        for (int i = 0; i < 6; ++i) {
            float vn = v[i] * inv;
            code_n[(size_t)row * C_ + lane + 64 * i] = vn;
            b_hi  [(size_t)row * C_ + lane + 64 * i] = f2bf(vn);
        }
        return;
    }
    __shared__ float tile[C_][17];
    __shared__ float red[16][17];
    __shared__ float s_inv[16];
    int b   = blockIdx.x / 49;
    int hw0 = (blockIdx.x - b * 49) * 16;
    int px  = tid & 15, cq = tid >> 4;

#pragma unroll
    for (int it = 0; it < 24; ++it) {
        int c = cq + 16 * it;
        tile[c][px] = feat[((size_t)(b * C_ + c)) * HW_ + hw0 + px];
    }
    __syncthreads();
    float ss = 0.f;
#pragma unroll
    for (int q = 0; q < 24; ++q) {
        float v = tile[cq + 16 * q][px];
        ss = fmaf(v, v, ss);
    }
    red[cq][px] = ss;
    __syncthreads();
    if (tid < 16) {
        float tot = 0.f;
#pragma unroll
        for (int p = 0; p < 16; ++p) tot += red[p][tid];
        float inv = 1.f / fmaxf(sqrtf(tot), 1e-12f);
        s_inv[tid] = inv;
        inv_n[(size_t)b * HW_ + hw0 + tid] = inv;
    }
    __syncthreads();

    {
        int p2 = tid >> 4, cc = tid & 15;
        float* fb = f_out + ((size_t)(b * HW_ + hw0 + p2)) * C_;
#pragma unroll
        for (int it = 0; it < 6; ++it) {
            int c0 = cc * 4 + 64 * it;
            f32x4 v;
            v[0] = tile[c0 + 0][p2];
            v[1] = tile[c0 + 1][p2];
            v[2] = tile[c0 + 2][p2];
            v[3] = tile[c0 + 3][p2];
            __builtin_nontemporal_store(v, (f32x4*)(fb + c0));
        }
    }
    {
        int p2 = tid >> 4, cc = tid & 15;
        float inv = s_inv[p2];
        u16* aptr = a_hi + ((size_t)(b * HW_ + hw0 + p2)) * C_;
#pragma unroll
        for (int it = 0; it < 12; ++it) {
            int c0 = 2 * cc + 32 * it;
            u16 h0 = f2bf(tile[c0][p2] * inv);
            u16 h1 = f2bf(tile[c0 + 1][p2] * inv);
            *(u32*)(aptr + c0) = (u32)h0 | ((u32)h1 << 16);
        }
    }
}

// ---------------- K2: bf16 MFMA GEMM; DB: also write bf16 dist shadow, NT fp32 dist ----------------
template <bool DB>
__global__ __launch_bounds__(256) void k_gemm(const u16* __restrict__ A,
                                              const u16* __restrict__ Bm,
                                              float* __restrict__ D,
                                              u16* __restrict__ db) {
    __shared__ u16 As[2][128 * 32];
    __shared__ u16 Bs[2][128 * 32];
    int tid = threadIdx.x;
    int lin = blockIdx.x;
    int swz = (lin & 7) * 392 + (lin >> 3);   // 3136 = 8 * 392, bijective
    int n0 = (swz & 15) * 128;
    int m0 = (swz >> 4) * 128;
    int w = tid >> 6, l = tid & 63;
    int wm = (w >> 1) * 64, wn = (w & 1) * 64;
    int q4 = l >> 4, r15 = l & 15;

    floatx4 acc[4][4];
#pragma unroll
    for (int i = 0; i < 4; ++i)
#pragma unroll
        for (int j = 0; j < 4; ++j) acc[i][j] = (floatx4)0.f;

    int srow = tid >> 2;
    int sp   = tid & 3;
    int fs   = (srow ^ (srow >> 2)) & 3;
    int kk0  = 8 * (sp ^ fs);

#define STAGE(buf, kt)                                                          \
    {                                                                           \
        _Pragma("unroll")                                                       \
        for (int q = 0; q < 2; ++q) {                                           \
            int row = q * 64 + srow;                                            \
            int off = (q * 256 + tid) * 16;                                     \
            gload_lds16(A  + (size_t)(m0 + row) * C_ + (kt) + kk0,              \
                        (char*)As[buf] + off);                                  \
            gload_lds16(Bm + (size_t)(n0 + row) * C_ + (kt) + kk0,              \
                        (char*)Bs[buf] + off);                                  \
        }                                                                       \
    }

    STAGE(0, 0);
    __syncthreads();

    const int slot = (q4 ^ ((r15 ^ (r15 >> 2)) & 3)) << 4;
#pragma unroll 1
    for (int t = 0; t < 12; ++t) {
        int cur = t & 1;
        if (t < 11) STAGE(cur ^ 1, (t + 1) * 32);
        const char* Ab = (const char*)As[cur];
        const char* Bb = (const char*)Bs[cur];
        short8 a[4], b[4];
#pragma unroll
        for (int i = 0; i < 4; ++i) {
            a[i] = *(const short8*)(Ab + (wm + i * 16 + r15) * 64 + slot);
            b[i] = *(const short8*)(Bb + (wn + i * 16 + r15) * 64 + slot);
        }
#pragma unroll
        for (int i = 0; i < 4; ++i)
#pragma unroll
            for (int j = 0; j < 4; ++j)
                acc[i][j] = __builtin_amdgcn_mfma_f32_16x16x32_bf16(a[i], b[j], acc[i][j], 0, 0, 0);
        __syncthreads();
    }

#pragma unroll
    for (int i = 0; i < 4; ++i) {
        int gm = m0 + wm + i * 16 + q4 * 4;
#pragma unroll
        for (int j = 0; j < 4; ++j) {
            int gn = n0 + wn + j * 16 + r15;
#pragma unroll
            for (int r = 0; r < 4; ++r) {
                float d = 2.f - 2.f * acc[i][j][r];
                if (DB) {
                    __builtin_nontemporal_store(d, D + (size_t)(gm + r) * K_ + gn);
                    db[(size_t)(gm + r) * K_ + gn] = f2bf(d);
                } else {
                    D[(size_t)(gm + r) * K_ + gn] = d;
                }
            }
        }
    }
#undef STAGE
}

// ---------------- K3: streaming row stats from bf16 shadow ----------------
__global__ __launch_bounds__(256) void k_stats_b(const u16* __restrict__ db,
                                                 float2* __restrict__ srow) {
    int row = blockIdx.x * 4 + (threadIdx.x >> 6);
    int l   = threadIdx.x & 63;
    const u16* dr = db + (size_t)row * K_;
    float es = 0.f, dm = 3.4e38f;
#pragma unroll
    for (int i = 0; i < 4; ++i) {
        u16x8 v = *(const u16x8*)(dr + l * 8 + 512 * i);
#pragma unroll
        for (int e = 0; e < 8; ++e) {
            float d = bf2f(v[e]);
            es += __expf(-10.f * d);
            dm = fminf(dm, d);
        }
    }
#pragma unroll
    for (int off = 32; off; off >>= 1) {
        es += __shfl_xor(es, off, 64);
        dm = fminf(dm, __shfl_xor(dm, off, 64));
    }
    if (l == 0) {
        float2 st;
        st.x = 1.f / es;
        st.y = dm + MARGIN;
        srow[row] = st;
    }
}

// fp32 fallback
__global__ __launch_bounds__(256) void k_stats_f(const float* __restrict__ D,
                                                 float2* __restrict__ srow) {
    int row = blockIdx.x * 4 + (threadIdx.x >> 6);
    int l   = threadIdx.x & 63;
    const float* dr = D + (size_t)row * K_;
    float es = 0.f, dm = 3.4e38f;
#pragma unroll
    for (int i = 0; i < 8; ++i) {
        float4 v = *(const float4*)(dr + l * 4 + 256 * i);
        es += __expf(-10.f * v.x) + __expf(-10.f * v.y)
            + __expf(-10.f * v.z) + __expf(-10.f * v.w);
        dm = fminf(dm, fminf(fminf(v.x, v.y), fminf(v.z, v.w)));
    }
#pragma unroll
    for (int off = 32; off; off >>= 1) {
        es += __shfl_xor(es, off, 64);
        dm = fminf(dm, __shfl_xor(dm, off, 64));
    }
    if (l == 0) {
        float2 st;
        st.x = 1.f / es;
        st.y = dm + MARGIN;
        srow[row] = st;
    }
}

// ---------------- K4: assignment + candidate collection (bf16 shadow) ----------------
__global__ __launch_bounds__(256) void k_post_b(const u16* __restrict__ db,
                                                const float2* __restrict__ srow,
                                                u32* __restrict__ Qi,
                                                float* __restrict__ asg) {
    __shared__ float tbuf[64][113];
    __shared__ float s_inv[PPX], s_thr[PPX];
    __shared__ int   s_cnt[PPX];
    __shared__ int   s_cand[PPX][16];
    int tile = blockIdx.x;
    int kc   = blockIdx.y;
    int b    = tile / 7;
    int hw0  = (tile - b * 7) * PPX;
    int n0   = b * HW_ + hw0;
    int tid  = threadIdx.x;

    if (tid < PPX) {
        float2 st = srow[n0 + tid];
        s_inv[tid] = st.x;
        s_thr[tid] = st.y;
        s_cnt[tid] = 0;
    }
    __syncthreads();

    int r16 = tid >> 4, c4 = (tid & 15) * 4;
    int px = tid & 127, kg = tid >> 7;
#pragma unroll 1
    for (int ch = 0; ch < 8; ++ch) {
        int k0 = kc * 512 + ch * 64;
#pragma unroll
        for (int rr = 0; rr < 7; ++rr) {
            int row = r16 + 16 * rr;
            u16x4 dv = *(const u16x4*)(db + (size_t)(n0 + row) * K_ + k0 + c4);
            float inv = s_inv[row], thr = s_thr[row];
#pragma unroll
            for (int cc = 0; cc < 4; ++cc) {
                float d = bf2f(dv[cc]);
                tbuf[c4 + cc][row] = __expf(-10.f * d) * inv;
                if (d <= thr) {
                    int idx = atomicAdd(&s_cnt[row], 1);
                    if (idx < 16) s_cand[row][idx] = k0 + c4 + cc;
                }
            }
        }
        __syncthreads();
        if (px < PPX) {
            size_t base = ((size_t)(b * K_ + k0 + kg * 32)) * HW_ + hw0 + px;
#pragma unroll
            for (int ki = 0; ki < 32; ++ki)
                __builtin_nontemporal_store(tbuf[kg * 32 + ki][px],
                                            asg + base + (size_t)ki * HW_);
        }
        __syncthreads();
    }

    if (tid < PPX) {
        int cnt = s_cnt[tid];
        cnt = cnt > 16 ? 16 : cnt;
        Qi[qslot(b, kc * 17, hw0 + tid)] = (u32)cnt;
        for (int ci = 0; ci < cnt; ++ci)
            Qi[qslot(b, kc * 17 + 1 + ci, hw0 + tid)] = (u32)s_cand[tid][ci];
    }
}

// fp32 fallback
__global__ __launch_bounds__(256) void k_post_f(const float* __restrict__ D,
                                                const float2* __restrict__ srow,
                                                u32* __restrict__ Qi,
                                                float* __restrict__ asg) {
    __shared__ float tbuf[64][113];
    __shared__ float s_inv[PPX], s_thr[PPX];
    __shared__ int   s_cnt[PPX];
    __shared__ int   s_cand[PPX][16];
    int tile = blockIdx.x;
    int kc   = blockIdx.y;
    int b    = tile / 7;
    int hw0  = (tile - b * 7) * PPX;
    int n0   = b * HW_ + hw0;
    int tid  = threadIdx.x;

    if (tid < PPX) {
        float2 st = srow[n0 + tid];
        s_inv[tid] = st.x;
        s_thr[tid] = st.y;
        s_cnt[tid] = 0;
    }
    __syncthreads();

    int r16 = tid >> 4, c4 = (tid & 15) * 4;
    int px = tid & 127, kg = tid >> 7;
#pragma unroll 1
    for (int ch = 0; ch < 8; ++ch) {
        int k0 = kc * 512 + ch * 64;
#pragma unroll
        for (int rr = 0; rr < 7; ++rr) {
            int row = r16 + 16 * rr;
            f32x4 dv = __builtin_nontemporal_load(
                (const f32x4*)(D + (size_t)(n0 + row) * K_ + k0 + c4));
            float inv = s_inv[row], thr = s_thr[row];
#pragma unroll
            for (int cc = 0; cc < 4; ++cc) {
                float d = dv[cc];
                tbuf[c4 + cc][row] = __expf(-10.f * d) * inv;
                if (d <= thr) {
                    int idx = atomicAdd(&s_cnt[row], 1);
                    if (idx < 16) s_cand[row][idx] = k0 + c4 + cc;
                }
            }
        }
        __syncthreads();
        if (px < PPX) {
            size_t base = ((size_t)(b * K_ + k0 + kg * 32)) * HW_ + hw0 + px;
#pragma unroll
            for (int ki = 0; ki < 32; ++ki)
                __builtin_nontemporal_store(tbuf[kg * 32 + ki][px],
                                            asg + base + (size_t)ki * HW_);
        }
        __syncthreads();
    }

    if (tid < PPX) {
        int cnt = s_cnt[tid];
        cnt = cnt > 16 ? 16 : cnt;
        Qi[qslot(b, kc * 17, hw0 + tid)] = (u32)cnt;
        for (int ci = 0; ci < cnt; ++ci)
            Qi[qslot(b, kc * 17 + 1 + ci, hw0 + tid)] = (u32)s_cand[tid][ci];
    }
}

// ---------------- K5: merge candidates, exact recheck, q gather ----------------
__global__ __launch_bounds__(256) void k_q(const u32* __restrict__ Qi,
                                           const float* __restrict__ codeN,
                                           const float* __restrict__ invN,
                                           const float* __restrict__ f_in,
                                           float* __restrict__ qOut) {
    __shared__ int s_amin[PPX], s_cnt[PPX];
    __shared__ int s_cand[PPX][64];
    int tile = blockIdx.x;
    int b    = tile / 7;
    int hw0  = (tile - b * 7) * PPX;
    int npix = b * HW_ + hw0;
    int tid  = threadIdx.x;

    if (tid < PPX) {
        int total = 0;
#pragma unroll
        for (int kc = 0; kc < 4; ++kc) {
            int cnt = (int)Qi[qslot(b, kc * 17, hw0 + tid)];
            for (int ci = 0; ci < cnt; ++ci)
                s_cand[tid][total++] = (int)Qi[qslot(b, kc * 17 + 1 + ci, hw0 + tid)];
        }
        s_cnt[tid]  = total;
        s_amin[tid] = s_cand[tid][0];
    }
    __syncthreads();

    int w = tid >> 6, l = tid & 63;
#pragma unroll 1
    for (int r = w; r < PPX; r += 4) {
        int cnt = s_cnt[r];
        if (cnt < 2) continue;
        float ivn = invN[npix + r];
        float fv[6];
        const float* frow = f_in + (size_t)(npix + r) * C_;
#pragma unroll
        for (int ii = 0; ii < 6; ++ii)
            fv[ii] = frow[l + 64 * ii] * ivn;
        float dbest = 3.4e38f;
        int   kbest = -1;
        for (int ci = 0; ci < cnt; ++ci) {
            int k = s_cand[r][ci];
            float dt = 0.f;
            const float* cr = codeN + (size_t)k * C_;
#pragma unroll
            for (int ii = 0; ii < 6; ++ii) dt = fmaf(fv[ii], cr[l + 64 * ii], dt);
#pragma unroll
            for (int off = 1; off < 64; off <<= 1) dt += __shfl_xor(dt, off, 64);
            float dex = 2.f - 2.f * dt;
            if (kbest < 0 || dex < dbest || (dex == dbest && k < kbest)) { dbest = dex; kbest = k; }
        }
        if (l == 0) s_amin[r] = kbest;
    }
    __syncthreads();

    int px = tid & 127, kg = tid >> 7;
    if (px < PPX) {
        const float* cr = codeN + (size_t)s_amin[px] * C_ + kg * 192;
        size_t qb = ((size_t)b * C_ + kg * 192) * HW_ + hw0 + px;
#pragma unroll 1
        for (int c4 = 0; c4 < 48; ++c4) {
            float4 v = *(const float4*)(cr + 4 * c4);
            __builtin_nontemporal_store(v.x, qOut + qb + (size_t)(4 * c4 + 0) * HW_);
            __builtin_nontemporal_store(v.y, qOut + qb + (size_t)(4 * c4 + 1) * HW_);
            __builtin_nontemporal_store(v.z, qOut + qb + (size_t)(4 * c4 + 2) * HW_);
            __builtin_nontemporal_store(v.w, qOut + qb + (size_t)(4 * c4 + 3) * HW_);
        }
    }
}

extern "C" void kernel_launch(void* const* d_in, const int* in_sizes, int n_in,
                              void* d_out, int out_size, void* d_ws, size_t ws_size,
                              hipStream_t stream) {
    const float* feat = (const float*)d_in[0];
    const float* cb   = (const float*)d_in[1];
    float* out    = (float*)d_out;
    float* f_out  = out + OFF_F;
    float* q_out  = out + OFF_Q;     // holds candidate scratch until k_q overwrites
    float* asg    = out + OFF_ASG;   // first 20.8 MB holds a_hi/b_hi until k_post
    float* dist   = out + OFF_DIST;

    u16* a_hi = (u16*)asg;
    u16* b_hi = a_hi + (size_t)N_ * C_;
    u32* Qi   = (u32*)q_out;

    const size_t DB_BYTES = (size_t)N_ * K_ * 2;          // 102,760,448
    bool big = ws_size >= DB_BYTES + 3145728 + 100352 + 200704;

    if (big) {
        u16*    db     = (u16*)d_ws;
        float*  code_n = (float*)((char*)d_ws + DB_BYTES);
        float*  inv_n  = (float*)((char*)d_ws + DB_BYTES + 3145728);
        float2* srow   = (float2*)((char*)d_ws + DB_BYTES + 3145728 + 100352);

        k_prep<<<2080, 256, 0, stream>>>(feat, cb, f_out, inv_n, a_hi, code_n, b_hi);
        k_gemm<true><<<3136, 256, 0, stream>>>(a_hi, b_hi, dist, db);
        k_stats_b<<<N_ / 4, 256, 0, stream>>>(db, srow);
        k_post_b<<<dim3(224, 4), 256, 0, stream>>>(db, srow, Qi, asg);
        k_q<<<224, 256, 0, stream>>>(Qi, code_n, inv_n, f_out, q_out);
    } else {
        float*  code_n = (float*)d_ws;
        float*  inv_n  = (float*)((char*)d_ws + 3145728);
        float2* srow   = (float2*)((char*)d_ws + 3246080);

        k_prep<<<2080, 256, 0, stream>>>(feat, cb, f_out, inv_n, a_hi, code_n, b_hi);
        k_gemm<false><<<3136, 256, 0, stream>>>(a_hi, b_hi, dist, nullptr);
        k_stats_f<<<N_ / 4, 256, 0, stream>>>(dist, srow);
        k_post_f<<<dim3(224, 4), 256, 0, stream>>>(dist, srow, Qi, asg);
        k_q<<<224, 256, 0, stream>>>(Qi, code_n, inv_n, f_out, q_out);
    }
}